// Round 7
// baseline (201.676 us; speedup 1.0000x reference)
//
#include <hip/hip_runtime.h>
#include <hip/hip_bf16.h>
#include <stdint.h>

#define SZ 3072
#define D_ 1024
#define BB 4
#define TT 8192
#define NROWS (BB * TT)   // 32768
#define CAP 128           // max rows per hash bucket (mean 10.7, Poisson tail safe)

typedef unsigned short u16;
typedef __bf16 bf16x8 __attribute__((ext_vector_type(8)));
typedef float f32x4 __attribute__((ext_vector_type(4)));

// ---- helpers ---------------------------------------------------------------

__device__ __forceinline__ u16 f2bf(float f) {
    union { float f; uint32_t u; } c;
    c.f = f;
    uint32_t u = c.u;
    uint32_t r = (u + 0x7FFFu + ((u >> 16) & 1u)) >> 16;   // RNE f32->bf16
    return (u16)r;
}

__device__ __forceinline__ void gload_lds16(const void* g, void* l) {
    // async global->LDS, 16B per lane. LDS dest must be wave-uniform base + lane*16.
    __builtin_amdgcn_global_load_lds(
        (__attribute__((address_space(1))) void*)(void*)g,
        (__attribute__((address_space(3))) void*)l,
        16, 0, 0);
}

__device__ __forceinline__ int hash_pair(int cur, int prev) {
    int a = (cur % SZ) * (31337 % SZ);      // 617
    int b = (prev % SZ) * (1000003 % SZ);   // 1603
    return (a + b) % SZ;                    // < 7M, int32-safe
}

// ---- kernel 1: fp32 -> bf16 convert of tab and w_proj ----------------------

__global__ __launch_bounds__(256) void convert_kernel(
    const float* __restrict__ tab, const float* __restrict__ w,
    u16* __restrict__ tabb, u16* __restrict__ wb) {
    const int NT4 = SZ * D_ / 4;
    const int NTOT = NT4 + D_ * D_ / 4;
    int i = blockIdx.x * 256 + threadIdx.x;
    if (i >= NTOT) return;
    const float4* src;
    u16* dst;
    int o;
    if (i < NT4) { src = (const float4*)tab; dst = tabb; o = i; }
    else         { src = (const float4*)w;   dst = wb;   o = i - NT4; }
    float4 v = src[o];
    unsigned long long pack =
        (unsigned long long)f2bf(v.x) |
        ((unsigned long long)f2bf(v.y) << 16) |
        ((unsigned long long)f2bf(v.z) << 32) |
        ((unsigned long long)f2bf(v.w) << 48);
    *(unsigned long long*)&dst[o * 4] = pack;
}

// ---- kernel 2: invert idx -> per-bucket row lists --------------------------

__global__ __launch_bounds__(256) void bucket_kernel(
    const int* __restrict__ t, int* __restrict__ count, int* __restrict__ lists) {
    int i = blockIdx.x * 256 + threadIdx.x;
    if (i >= NROWS) return;
    int j = i & (TT - 1);
    int cur = t[i];
    int prev = (j == 0) ? 0 : t[i - 1];
    int s = hash_pair(cur, prev);
    int pos = atomicAdd(&count[s], 1);
    if (pos < CAP) lists[s * CAP + pos] = i;   // order irrelevant: same P row
}

// ---- kernel 3: fused GEMM + scatter ----------------------------------------
// P-tile[s,e] = sum_d tab[s,d]*w[e,d] computed in-register, staged to LDS,
// then written directly to every out row with idx==s (no P buffer round-trip).

__global__ __launch_bounds__(256) void gemm_scatter_kernel(
    const u16* __restrict__ Ab,      // [SZ][D_] bf16 bits
    const u16* __restrict__ Wb,      // [D_][D_] bf16 bits
    const int* __restrict__ count,   // [SZ]
    const int* __restrict__ lists,   // [SZ][CAP]
    float* __restrict__ out) {       // [NROWS][D_]
    __shared__ __align__(16) u16 As[64][32];
    __shared__ __align__(16) u16 Ws[64][32];
    __shared__ __align__(16) float tile[64][68];   // 68: pad keeps rows 16B-aligned

    // bijective XCD-chunked swizzle (nwg=768, 768%8==0)
    const int bid = blockIdx.x;
    const int wgid = (bid & 7) * 96 + (bid >> 3);
    const int brow = wgid >> 4;         // 48 row-tiles
    const int bcol = wgid & 15;         // 16 col-tiles
    const int row0 = brow << 6;
    const int col0 = bcol << 6;

    const int tid = threadIdx.x;
    const int lane = tid & 63;
    const int w = tid >> 6;             // wave 0..3 in 2x2 grid of 32x32 subtiles
    const int wr = (w >> 1) << 5;
    const int wc = (w & 1) << 5;
    const int lrow = lane & 15;
    const int k8 = (lane >> 4) << 3;

    const int r0 = tid >> 2, kk0 = (tid & 3) << 3;   // staging chunk -> LDS tid*16

    f32x4 acc[2][2];
#pragma unroll
    for (int m = 0; m < 2; ++m)
#pragma unroll
        for (int n = 0; n < 2; ++n)
            acc[m][n] = f32x4{0.f, 0.f, 0.f, 0.f};

    for (int k0 = 0; k0 < D_; k0 += 32) {
        gload_lds16(&Ab[(row0 + r0) * D_ + k0 + kk0], &As[r0][kk0]);
        gload_lds16(&Wb[(col0 + r0) * D_ + k0 + kk0], &Ws[r0][kk0]);
        __syncthreads();

        bf16x8 av[2], bv[2];
#pragma unroll
        for (int m = 0; m < 2; ++m)
            av[m] = *(const bf16x8*)&As[wr + m * 16 + lrow][k8];
#pragma unroll
        for (int n = 0; n < 2; ++n)
            bv[n] = *(const bf16x8*)&Ws[wc + n * 16 + lrow][k8];
#pragma unroll
        for (int m = 0; m < 2; ++m)
#pragma unroll
            for (int n = 0; n < 2; ++n)
                acc[m][n] = __builtin_amdgcn_mfma_f32_16x16x32_bf16(
                    av[m], bv[n], acc[m][n], 0, 0, 0);
        __syncthreads();
    }

    // stage tile to LDS. C/D layout: col=lane&15, row=4*(lane>>4)+reg [m89]
    const int rbase = (lane >> 4) << 2;
#pragma unroll
    for (int m = 0; m < 2; ++m)
#pragma unroll
        for (int n = 0; n < 2; ++n)
#pragma unroll
            for (int r = 0; r < 4; ++r)
                tile[wr + m * 16 + rbase + r][wc + n * 16 + lrow] = acc[m][n][r];
    __syncthreads();

    // scatter: for each source row r, copy the 256B col-slice to all dup rows.
    // thread t handles duplicate (t>>4), float4-column (t&15). Writes are
    // 16-lane x 16B = 256B contiguous segments -> coalesced.
    const int dup = tid >> 4;
    const int c4 = (tid & 15) << 2;
    for (int r = 0; r < 64; ++r) {
        int s = row0 + r;                  // block-uniform -> scalar loads
        int cnt = count[s];
        f32x4 val = *(const f32x4*)&tile[r][c4];
        for (int base = 0; base < cnt; base += 16) {
            int d = base + dup;
            if (d < cnt) {
                int orow = lists[s * CAP + d];
                __builtin_nontemporal_store(
                    val, (f32x4*)&out[(size_t)orow * D_ + col0 + c4]);
            }
        }
    }
}

// ---- fallback (only if ws too small): direct fp32 compute ------------------

__global__ __launch_bounds__(256) void fallback_kernel(
    const int* __restrict__ t, const float* __restrict__ tab,
    const float* __restrict__ w, float* __restrict__ out) {
    __shared__ float emb[D_];
    int row = blockIdx.x;
    int j = row & (TT - 1);
    int cur = t[row];
    int prev = (j == 0) ? 0 : t[row - 1];
    int s = hash_pair(cur, prev);
    for (int d = threadIdx.x; d < D_; d += 256) emb[d] = tab[s * D_ + d];
    __syncthreads();
    for (int e = threadIdx.x; e < D_; e += 256) {
        float accv = 0.f;
        const float* wrow = &w[e * D_];
        for (int d = 0; d < D_; ++d) accv += emb[d] * wrow[d];
        out[(size_t)row * D_ + e] = accv;
    }
}

// ---- launch ---------------------------------------------------------------

extern "C" void kernel_launch(void* const* d_in, const int* in_sizes, int n_in,
                              void* d_out, int out_size, void* d_ws, size_t ws_size,
                              hipStream_t stream) {
    const int* t = (const int*)d_in[0];
    const float* tab = (const float*)d_in[1];
    const float* w = (const float*)d_in[2];
    float* out = (float*)d_out;

    const size_t off_tabb  = 0;
    const size_t off_wb    = (size_t)SZ * D_ * 2;             // 6,291,456
    const size_t off_count = off_wb + (size_t)D_ * D_ * 2;    // 8,388,608
    const size_t off_lists = off_count + (size_t)SZ * 4;      // 8,400,896
    const size_t need      = off_lists + (size_t)SZ * CAP * 4; // 9,973,760

    if (ws_size < need) {
        fallback_kernel<<<NROWS, 256, 0, stream>>>(t, tab, w, out);
        return;
    }

    u16* tabb  = (u16*)((char*)d_ws + off_tabb);
    u16* wb    = (u16*)((char*)d_ws + off_wb);
    int* count = (int*)((char*)d_ws + off_count);
    int* lists = (int*)((char*)d_ws + off_lists);

    hipMemsetAsync(count, 0, (size_t)SZ * 4, stream);        // capturable
    convert_kernel<<<4096, 256, 0, stream>>>(tab, w, tabb, wb);
    bucket_kernel<<<NROWS / 256, 256, 0, stream>>>(t, count, lists);
    gemm_scatter_kernel<<<(SZ / 64) * (D_ / 64), 256, 0, stream>>>(
        tabb, wb, count, lists, out);
}

// Round 9
// 190.369 us; speedup vs baseline: 1.0594x; 1.0594x over previous
//
#include <hip/hip_runtime.h>
#include <hip/hip_bf16.h>
#include <stdint.h>

#define SZ 3072
#define D_ 1024
#define BB 4
#define TT 8192
#define NROWS (BB * TT)   // 32768

typedef unsigned short u16;
typedef __bf16 bf16x8 __attribute__((ext_vector_type(8)));
typedef float f32x4 __attribute__((ext_vector_type(4)));

// ---- helpers ---------------------------------------------------------------

__device__ __forceinline__ u16 f2bf(float f) {
    union { float f; uint32_t u; } c;
    c.f = f;
    uint32_t u = c.u;
    uint32_t r = (u + 0x7FFFu + ((u >> 16) & 1u)) >> 16;   // RNE f32->bf16
    return (u16)r;
}

__device__ __forceinline__ void gload_lds16(const void* g, void* l) {
    // async global->LDS, 16B per lane. LDS dest must be wave-uniform base + lane*16.
    __builtin_amdgcn_global_load_lds(
        (__attribute__((address_space(1))) void*)(void*)g,
        (__attribute__((address_space(3))) void*)l,
        16, 0, 0);
}

__device__ __forceinline__ int hash_pair(int cur, int prev) {
    int a = (cur % SZ) * (31337 % SZ);      // 617
    int b = (prev % SZ) * (1000003 % SZ);   // 1603
    return (a + b) % SZ;                    // < 7M, int32-safe
}

// ---- kernel 1: fp32 -> bf16 convert of tab and w_proj ----------------------

__global__ __launch_bounds__(256) void convert_kernel(
    const float* __restrict__ tab, const float* __restrict__ w,
    u16* __restrict__ tabb, u16* __restrict__ wb) {
    const int NT4 = SZ * D_ / 4;
    const int NTOT = NT4 + D_ * D_ / 4;
    int i = blockIdx.x * 256 + threadIdx.x;
    if (i >= NTOT) return;
    const float4* src;
    u16* dst;
    int o;
    if (i < NT4) { src = (const float4*)tab; dst = tabb; o = i; }
    else         { src = (const float4*)w;   dst = wb;   o = i - NT4; }
    float4 v = src[o];
    unsigned long long pack =
        (unsigned long long)f2bf(v.x) |
        ((unsigned long long)f2bf(v.y) << 16) |
        ((unsigned long long)f2bf(v.z) << 32) |
        ((unsigned long long)f2bf(v.w) << 48);
    *(unsigned long long*)&dst[o * 4] = pack;
}

// ---- kernel 2: P[s,e] = sum_d tab[s,d]*w[e,d]  (64x64 tiles, 2-phase dbuf) -
// 768 blocks (3/CU). Double-buffered LDS; counted vmcnt(2) keeps next K-tile's
// global_load_lds in flight under current tile's MFMA (T3 minimum-2-phase).

__global__ __launch_bounds__(256) void gemm_p_kernel(
    const u16* __restrict__ Ab,   // [SZ][D_] bf16 bits
    const u16* __restrict__ Wb,   // [D_][D_] bf16 bits
    float* __restrict__ P) {      // [SZ][D_]
    __shared__ __align__(16) u16 As[2][64][32];
    __shared__ __align__(16) u16 Ws[2][64][32];

    // bijective XCD-chunked swizzle (nwg=768, 768%8==0)
    const int bid = blockIdx.x;
    const int wgid = (bid & 7) * 96 + (bid >> 3);
    const int brow = wgid >> 4;         // 48 row-tiles
    const int bcol = wgid & 15;         // 16 col-tiles
    const int row0 = brow << 6;
    const int col0 = bcol << 6;

    const int tid = threadIdx.x;
    const int lane = tid & 63;
    const int w = tid >> 6;             // wave 0..3 in 2x2 grid of 32x32 subtiles
    const int wr = (w >> 1) << 5;
    const int wc = (w & 1) << 5;
    const int lrow = lane & 15;
    const int k8 = (lane >> 4) << 3;

    // staging chunk tid -> row tid>>2, col (tid&3)*8; LDS byte addr = tid*16
    const int r0 = tid >> 2, kk0 = (tid & 3) << 3;
    const u16* ga = &Ab[(row0 + r0) * D_ + kk0];
    const u16* gw = &Wb[(col0 + r0) * D_ + kk0];

    f32x4 acc[2][2];
#pragma unroll
    for (int m = 0; m < 2; ++m)
#pragma unroll
        for (int n = 0; n < 2; ++n)
            acc[m][n] = f32x4{0.f, 0.f, 0.f, 0.f};

    // prologue: stage K-tile 0 into buffer 0
    gload_lds16(ga, &As[0][r0][kk0]);
    gload_lds16(gw, &Ws[0][r0][kk0]);

#define KSTEP(BUF, KT)                                                        \
    {                                                                         \
        if ((KT) < 31) {                                                      \
            const int koff = ((KT) + 1) << 5;                                 \
            gload_lds16(ga + koff, &As[(BUF) ^ 1][r0][kk0]);                  \
            gload_lds16(gw + koff, &Ws[(BUF) ^ 1][r0][kk0]);                  \
            asm volatile("s_waitcnt vmcnt(2)" ::: "memory");                  \
        } else {                                                              \
            asm volatile("s_waitcnt vmcnt(0)" ::: "memory");                  \
        }                                                                     \
        __builtin_amdgcn_s_barrier();                                         \
        __builtin_amdgcn_sched_barrier(0);                                    \
        bf16x8 av0 = *(const bf16x8*)&As[BUF][wr + lrow][k8];                 \
        bf16x8 av1 = *(const bf16x8*)&As[BUF][wr + 16 + lrow][k8];            \
        bf16x8 bv0 = *(const bf16x8*)&Ws[BUF][wc + lrow][k8];                 \
        bf16x8 bv1 = *(const bf16x8*)&Ws[BUF][wc + 16 + lrow][k8];            \
        acc[0][0] = __builtin_amdgcn_mfma_f32_16x16x32_bf16(av0, bv0, acc[0][0], 0, 0, 0); \
        acc[0][1] = __builtin_amdgcn_mfma_f32_16x16x32_bf16(av0, bv1, acc[0][1], 0, 0, 0); \
        acc[1][0] = __builtin_amdgcn_mfma_f32_16x16x32_bf16(av1, bv0, acc[1][0], 0, 0, 0); \
        acc[1][1] = __builtin_amdgcn_mfma_f32_16x16x32_bf16(av1, bv1, acc[1][1], 0, 0, 0); \
        __builtin_amdgcn_sched_barrier(0);                                    \
        __builtin_amdgcn_s_barrier();                                         \
    }

    for (int kt = 0; kt < 32; kt += 2) {
        KSTEP(0, kt);
        KSTEP(1, kt + 1);
    }
#undef KSTEP

    // C/D layout: col = lane&15, row = 4*(lane>>4) + reg   [m89-verified]
    const int rbase = (lane >> 4) << 2;
#pragma unroll
    for (int m = 0; m < 2; ++m)
#pragma unroll
        for (int n = 0; n < 2; ++n)
#pragma unroll
            for (int r = 0; r < 4; ++r)
                P[(row0 + wr + m * 16 + rbase + r) * D_ + col0 + wc + n * 16 + lrow] =
                    acc[m][n][r];
}

// ---- kernel 3: out[row] = P[hash(t[row], t[row-1])]  (fused hash + gather) -

__global__ __launch_bounds__(256) void gather_kernel(
    const float* __restrict__ P, const int* __restrict__ t,
    float* __restrict__ out) {
    const int total = NROWS * (D_ / 4);   // 8,388,608 float4s
    const f32x4* P4 = (const f32x4*)P;
    f32x4* O4 = (f32x4*)out;
    for (int v = blockIdx.x * 256 + threadIdx.x; v < total; v += gridDim.x * 256) {
        int row = v >> 8;      // uniform per (block, iter); 256 float4s per row
        int c4 = v & 255;
        int cur = t[row];
        int prev = ((row & (TT - 1)) == 0) ? 0 : t[row - 1];
        int s = hash_pair(cur, prev);
        f32x4 val = P4[s * 256 + c4];
        // non-temporal: 128 MiB output stream must not evict P from L2
        __builtin_nontemporal_store(val, &O4[v]);
    }
}

// ---- fallback (only if ws too small): direct fp32 compute ------------------

__global__ __launch_bounds__(256) void fallback_kernel(
    const int* __restrict__ t, const float* __restrict__ tab,
    const float* __restrict__ w, float* __restrict__ out) {
    __shared__ float emb[D_];
    int row = blockIdx.x;
    int j = row & (TT - 1);
    int cur = t[row];
    int prev = (j == 0) ? 0 : t[row - 1];
    int s = hash_pair(cur, prev);
    for (int d = threadIdx.x; d < D_; d += 256) emb[d] = tab[s * D_ + d];
    __syncthreads();
    for (int e = threadIdx.x; e < D_; e += 256) {
        float accv = 0.f;
        const float* wrow = &w[e * D_];
        for (int d = 0; d < D_; ++d) accv += emb[d] * wrow[d];
        out[(size_t)row * D_ + e] = accv;
    }
}

// ---- launch ---------------------------------------------------------------

extern "C" void kernel_launch(void* const* d_in, const int* in_sizes, int n_in,
                              void* d_out, int out_size, void* d_ws, size_t ws_size,
                              hipStream_t stream) {
    const int* t = (const int*)d_in[0];
    const float* tab = (const float*)d_in[1];
    const float* w = (const float*)d_in[2];
    float* out = (float*)d_out;

    const size_t off_tabb = 0;
    const size_t off_wb   = (size_t)SZ * D_ * 2;            //  6,291,456
    const size_t off_P    = off_wb + (size_t)D_ * D_ * 2;   //  8,388,608
    const size_t need     = off_P + (size_t)SZ * D_ * 4;    // 20,971,520

    if (ws_size < need) {
        fallback_kernel<<<NROWS, 256, 0, stream>>>(t, tab, w, out);
        return;
    }

    u16* tabb = (u16*)((char*)d_ws + off_tabb);
    u16* wb   = (u16*)((char*)d_ws + off_wb);
    float* P  = (float*)((char*)d_ws + off_P);

    convert_kernel<<<4096, 256, 0, stream>>>(tab, w, tabb, wb);
    gemm_p_kernel<<<(SZ / 64) * (D_ / 64), 256, 0, stream>>>(tabb, wb, P);
    gather_kernel<<<2048, 256, 0, stream>>>(P, t, out);
}

// Round 10
// 179.073 us; speedup vs baseline: 1.1262x; 1.0631x over previous
//
#include <hip/hip_runtime.h>
#include <hip/hip_bf16.h>
#include <stdint.h>

#define SZ 3072
#define D_ 1024
#define BB 4
#define TT 8192
#define NROWS (BB * TT)   // 32768

typedef unsigned short u16;
typedef __bf16 bf16x8 __attribute__((ext_vector_type(8)));
typedef float f32x4 __attribute__((ext_vector_type(4)));

// ---- helpers ---------------------------------------------------------------

__device__ __forceinline__ u16 f2bf(float f) {
    union { float f; uint32_t u; } c;
    c.f = f;
    uint32_t u = c.u;
    uint32_t r = (u + 0x7FFFu + ((u >> 16) & 1u)) >> 16;   // RNE f32->bf16
    return (u16)r;
}

__device__ __forceinline__ float bf2f(u16 h) {
    union { uint32_t u; float f; } c;
    c.u = ((uint32_t)h) << 16;        // bit-exact bf16 -> f32
    return c.f;
}

__device__ __forceinline__ void gload_lds16(const void* g, void* l) {
    // async global->LDS, 16B per lane. LDS dest must be wave-uniform base + lane*16.
    __builtin_amdgcn_global_load_lds(
        (__attribute__((address_space(1))) void*)(void*)g,
        (__attribute__((address_space(3))) void*)l,
        16, 0, 0);
}

__device__ __forceinline__ int hash_pair(int cur, int prev) {
    int a = (cur % SZ) * (31337 % SZ);      // 617
    int b = (prev % SZ) * (1000003 % SZ);   // 1603
    return (a + b) % SZ;                    // < 7M, int32-safe
}

// ---- kernel 1: fp32 -> bf16 convert of tab and w_proj ----------------------

__global__ __launch_bounds__(256) void convert_kernel(
    const float* __restrict__ tab, const float* __restrict__ w,
    u16* __restrict__ tabb, u16* __restrict__ wb) {
    const int NT4 = SZ * D_ / 4;
    const int NTOT = NT4 + D_ * D_ / 4;
    int i = blockIdx.x * 256 + threadIdx.x;
    if (i >= NTOT) return;
    const float4* src;
    u16* dst;
    int o;
    if (i < NT4) { src = (const float4*)tab; dst = tabb; o = i; }
    else         { src = (const float4*)w;   dst = wb;   o = i - NT4; }
    float4 v = src[o];
    unsigned long long pack =
        (unsigned long long)f2bf(v.x) |
        ((unsigned long long)f2bf(v.y) << 16) |
        ((unsigned long long)f2bf(v.z) << 32) |
        ((unsigned long long)f2bf(v.w) << 48);
    *(unsigned long long*)&dst[o * 4] = pack;
}

// ---- kernel 2: P[s,e] = sum_d tab[s,d]*w[e,d]  (bf16 MFMA, 64x64 tiles) ----
// 768 blocks (3/CU co-resident); single-buffer (dbuf measured neutral, R9).
// P stored as bf16: halves gather read traffic + P fits L2 better.

__global__ __launch_bounds__(256) void gemm_p_kernel(
    const u16* __restrict__ Ab,   // [SZ][D_] bf16 bits
    const u16* __restrict__ Wb,   // [D_][D_] bf16 bits
    u16* __restrict__ Pb) {       // [SZ][D_] bf16 bits
    __shared__ __align__(16) u16 As[64][32];
    __shared__ __align__(16) u16 Ws[64][32];

    // bijective XCD-chunked swizzle (nwg=768, 768%8==0)
    const int bid = blockIdx.x;
    const int wgid = (bid & 7) * 96 + (bid >> 3);
    const int brow = wgid >> 4;         // 48 row-tiles
    const int bcol = wgid & 15;         // 16 col-tiles
    const int row0 = brow << 6;
    const int col0 = bcol << 6;

    const int tid = threadIdx.x;
    const int lane = tid & 63;
    const int w = tid >> 6;             // wave 0..3 in 2x2 grid of 32x32 subtiles
    const int wr = (w >> 1) << 5;
    const int wc = (w & 1) << 5;
    const int lrow = lane & 15;
    const int k8 = (lane >> 4) << 3;

    // staging chunk tid -> row tid>>2, col (tid&3)*8; LDS byte addr = tid*16
    const int r0 = tid >> 2, kk0 = (tid & 3) << 3;

    f32x4 acc[2][2];
#pragma unroll
    for (int m = 0; m < 2; ++m)
#pragma unroll
        for (int n = 0; n < 2; ++n)
            acc[m][n] = f32x4{0.f, 0.f, 0.f, 0.f};

    for (int k0 = 0; k0 < D_; k0 += 32) {
        gload_lds16(&Ab[(row0 + r0) * D_ + k0 + kk0], &As[r0][kk0]);
        gload_lds16(&Wb[(col0 + r0) * D_ + k0 + kk0], &Ws[r0][kk0]);
        __syncthreads();

        bf16x8 av[2], bv[2];
#pragma unroll
        for (int m = 0; m < 2; ++m)
            av[m] = *(const bf16x8*)&As[wr + m * 16 + lrow][k8];
#pragma unroll
        for (int n = 0; n < 2; ++n)
            bv[n] = *(const bf16x8*)&Ws[wc + n * 16 + lrow][k8];
#pragma unroll
        for (int m = 0; m < 2; ++m)
#pragma unroll
            for (int n = 0; n < 2; ++n)
                acc[m][n] = __builtin_amdgcn_mfma_f32_16x16x32_bf16(
                    av[m], bv[n], acc[m][n], 0, 0, 0);
        __syncthreads();
    }

    // C/D layout: col = lane&15, row = 4*(lane>>4) + reg   [m89-verified]
    const int rbase = (lane >> 4) << 2;
#pragma unroll
    for (int m = 0; m < 2; ++m)
#pragma unroll
        for (int n = 0; n < 2; ++n)
#pragma unroll
            for (int r = 0; r < 4; ++r)
                Pb[(row0 + wr + m * 16 + rbase + r) * D_ + col0 + wc + n * 16 + lrow] =
                    f2bf(acc[m][n][r]);
}

// ---- kernel 3: out[row] = f32(Pb[hash(t[row], t[row-1])])  -----------------
// One block per row per iteration: 256 threads x 4 elems = 1024.
// Read 2 KiB bf16 (L2/L3-resident), widen in-register, NT-write 4 KiB.

__global__ __launch_bounds__(256) void gather_kernel(
    const u16* __restrict__ Pb, const int* __restrict__ t,
    float* __restrict__ out) {
    for (int row = blockIdx.x; row < NROWS; row += gridDim.x) {
        int cur = t[row];
        int prev = ((row & (TT - 1)) == 0) ? 0 : t[row - 1];
        int s = hash_pair(cur, prev);
        ushort4 hv = ((const ushort4*)&Pb[(size_t)s * D_])[threadIdx.x];
        f32x4 val;
        val[0] = bf2f(hv.x);
        val[1] = bf2f(hv.y);
        val[2] = bf2f(hv.z);
        val[3] = bf2f(hv.w);
        // non-temporal: 128 MiB output stream must not evict Pb from L2
        __builtin_nontemporal_store(
            val, &((f32x4*)&out[(size_t)row * D_])[threadIdx.x]);
    }
}

// ---- fallback (only if ws too small): direct fp32 compute ------------------

__global__ __launch_bounds__(256) void fallback_kernel(
    const int* __restrict__ t, const float* __restrict__ tab,
    const float* __restrict__ w, float* __restrict__ out) {
    __shared__ float emb[D_];
    int row = blockIdx.x;
    int j = row & (TT - 1);
    int cur = t[row];
    int prev = (j == 0) ? 0 : t[row - 1];
    int s = hash_pair(cur, prev);
    for (int d = threadIdx.x; d < D_; d += 256) emb[d] = tab[s * D_ + d];
    __syncthreads();
    for (int e = threadIdx.x; e < D_; e += 256) {
        float accv = 0.f;
        const float* wrow = &w[e * D_];
        for (int d = 0; d < D_; ++d) accv += emb[d] * wrow[d];
        out[(size_t)row * D_ + e] = accv;
    }
}

// ---- launch ---------------------------------------------------------------

extern "C" void kernel_launch(void* const* d_in, const int* in_sizes, int n_in,
                              void* d_out, int out_size, void* d_ws, size_t ws_size,
                              hipStream_t stream) {
    const int* t = (const int*)d_in[0];
    const float* tab = (const float*)d_in[1];
    const float* w = (const float*)d_in[2];
    float* out = (float*)d_out;

    const size_t off_tabb = 0;
    const size_t off_wb   = (size_t)SZ * D_ * 2;            //  6,291,456
    const size_t off_Pb   = off_wb + (size_t)D_ * D_ * 2;   //  8,388,608
    const size_t need     = off_Pb + (size_t)SZ * D_ * 2;   // 14,680,064

    if (ws_size < need) {
        fallback_kernel<<<NROWS, 256, 0, stream>>>(t, tab, w, out);
        return;
    }

    u16* tabb = (u16*)((char*)d_ws + off_tabb);
    u16* wb   = (u16*)((char*)d_ws + off_wb);
    u16* Pb   = (u16*)((char*)d_ws + off_Pb);

    convert_kernel<<<4096, 256, 0, stream>>>(tab, w, tabb, wb);
    gemm_p_kernel<<<(SZ / 64) * (D_ / 64), 256, 0, stream>>>(tabb, wb, Pb);
    gather_kernel<<<2048, 256, 0, stream>>>(Pb, t, out);
}